// Round 8
// baseline (73.177 us; speedup 1.0000x reference)
//
#include <hip/hip_runtime.h>

// out[b][j] = sum_i spikes[b][i] * W[i][j]
//   spikes [8,8192] f32, W [8192,8192] f32 row-major, out [8,8192] f32.
// History:
//  R1 (float2, 8x ds_read_b32, 4.2M atomics): 86us.
//  R2/R3 (float4, acc ARRAY): 202-206us — array demoted to scratch (VGPR=36),
//    plus 8.4M atomicAdds = 134MB memory-side RMW.
//  R4 (named float4 accs + two-stage split-K, no atomics): 58.5us.
//  R5 (stage-2 full-width): 58.2us — NEUTRAL.
//  R6/R7 (nontemporal partials): POST-TIMING DIVERGENCE (0.54 = one stale
//    k-chunk partial). nt stores/loads on a cross-kernel producer->consumer
//    path break the dispatch-boundary coherence that plain accesses get
//    (cross-XCD L2s). NEVER nt data another kernel reads. Reverted.
//  R8: R5's plain-access structure + KCHUNK 128->256 (partial round-trip
//      33.6MB -> 16.8MB; grid 256 blocks = 1/CU).

constexpr int N_PREV = 8192;
constexpr int N_HID  = 8192;
constexpr int BATCH  = 8;
constexpr int TPB    = 256;
constexpr int CPT    = 4;                      // cols per thread (float4)
constexpr int COLS_PER_BLOCK = TPB * CPT;      // 1024
constexpr int KCHUNK = 256;
constexpr int NKC    = N_PREV / KCHUNK;        // 32 k-chunks
constexpr int OUT_ELEMS = BATCH * N_HID;       // 65536

#define FMA4(A, S) \
  A.x += (S) * w.x; A.y += (S) * w.y; A.z += (S) * w.z; A.w += (S) * w.w;

template <bool USE_ATOMIC>
__global__ __launch_bounds__(TPB) void snn_stage1(
    const float* __restrict__ spikes,
    const float* __restrict__ W,
    float* __restrict__ dst) {        // partial buffer, or out if USE_ATOMIC
  __shared__ float s_sp[KCHUNK][BATCH];        // k-major spikes chunk (8KB)

  const int cb  = blockIdx.x;
  const int p   = blockIdx.y;                  // k-chunk index
  const int k0  = p * KCHUNK;
  const int col = cb * COLS_PER_BLOCK + threadIdx.x * CPT;

  // Stage spikes chunk transposed; thread t writes float #t -> conflict-free.
  for (int t = threadIdx.x; t < KCHUNK * BATCH; t += TPB) {
    const int k = t >> 3, b = t & 7;
    s_sp[k][b] = spikes[b * N_PREV + k0 + k];
  }
  __syncthreads();

  // Named accumulators: guaranteed VGPRs (no private arrays anywhere).
  float4 a0 = {0,0,0,0}, a1 = {0,0,0,0}, a2 = {0,0,0,0}, a3 = {0,0,0,0};
  float4 a4 = {0,0,0,0}, a5 = {0,0,0,0}, a6 = {0,0,0,0}, a7 = {0,0,0,0};

  const float* wp = W + (size_t)k0 * N_HID + col;
  #pragma unroll 8
  for (int k = 0; k < KCHUNK; ++k) {
    const float4 w = *reinterpret_cast<const float4*>(wp);
    wp += N_HID;
    const float4 slo = *reinterpret_cast<const float4*>(&s_sp[k][0]); // b128 bcast
    const float4 shi = *reinterpret_cast<const float4*>(&s_sp[k][4]); // b128 bcast
    FMA4(a0, slo.x) FMA4(a1, slo.y) FMA4(a2, slo.z) FMA4(a3, slo.w)
    FMA4(a4, shi.x) FMA4(a5, shi.y) FMA4(a6, shi.z) FMA4(a7, shi.w)
  }

  if constexpr (USE_ATOMIC) {
    #define EMIT(b, A) { float* op = &dst[(b) * N_HID + col]; \
      atomicAdd(op+0, A.x); atomicAdd(op+1, A.y);             \
      atomicAdd(op+2, A.z); atomicAdd(op+3, A.w); }
    EMIT(0, a0) EMIT(1, a1) EMIT(2, a2) EMIT(3, a3)
    EMIT(4, a4) EMIT(5, a5) EMIT(6, a6) EMIT(7, a7)
    #undef EMIT
  } else {
    float* base = dst + (size_t)p * OUT_ELEMS + col;
    #define EMIT(b, A) *reinterpret_cast<float4*>(base + (b) * N_HID) = A;
    EMIT(0, a0) EMIT(1, a1) EMIT(2, a2) EMIT(3, a3)
    EMIT(4, a4) EMIT(5, a5) EMIT(6, a6) EMIT(7, a7)
    #undef EMIT
  }
}

// out[j4] = sum_p partial[p][j4]. One float4 per thread, 256 blocks x 64 thr.
constexpr int TPB2 = 64;

__global__ __launch_bounds__(TPB2) void snn_stage2(
    const float* __restrict__ partial, float* __restrict__ out) {
  const int j4 = blockIdx.x * TPB2 + threadIdx.x;    // 0..16383
  const float4* p4 = reinterpret_cast<const float4*>(partial) + j4;
  float4 s = {0,0,0,0};
  #pragma unroll 8
  for (int p = 0; p < NKC; ++p) {
    const float4 v = p4[(size_t)p * (OUT_ELEMS / 4)];
    s.x += v.x; s.y += v.y; s.z += v.z; s.w += v.w;
  }
  reinterpret_cast<float4*>(out)[j4] = s;
}

extern "C" void kernel_launch(void* const* d_in, const int* in_sizes, int n_in,
                              void* d_out, int out_size, void* d_ws, size_t ws_size,
                              hipStream_t stream) {
  const float* spikes = (const float*)d_in[0];   // [8, 8192]
  const float* W      = (const float*)d_in[1];   // [8192, 8192]
  float* out          = (float*)d_out;           // [8, 8192]
  float* partial      = (float*)d_ws;

  const size_t need = (size_t)NKC * OUT_ELEMS * sizeof(float);  // 8.4 MB
  dim3 grid(N_HID / COLS_PER_BLOCK, NKC);        // (8, 32) = 256 blocks
  dim3 block(TPB);

  if (ws_size >= need) {
    snn_stage1<false><<<grid, block, 0, stream>>>(spikes, W, partial);
    snn_stage2<<<dim3(OUT_ELEMS / 4 / TPB2), dim3(TPB2), 0, stream>>>(partial, out);
  } else {
    // Fallback: atomics into zeroed out (deterministic host-side branch).
    (void)hipMemsetAsync(out, 0, (size_t)out_size * sizeof(float), stream);
    snn_stage1<true><<<grid, block, 0, stream>>>(spikes, W, out);
  }
}

// Round 9
// 62.132 us; speedup vs baseline: 1.1778x; 1.1778x over previous
//
#include <hip/hip_runtime.h>

// out[b][j] = sum_i spikes[b][i] * W[i][j]
//   spikes [8,8192] f32, W [8192,8192] f32 row-major, out [8,8192] f32.
// History:
//  R1 (float2, scalar LDS, atomics): 86us.
//  R2/R3 (acc ARRAY -> scratch + 8.4M atomics): 202-206us.
//  R4 (named float4 accs + two-stage split-K): 58.5us. R5 (wide stage-2): 58.2.
//  R6/R7 (nontemporal partials): post-timing divergence — nt breaks
//    cross-kernel producer->consumer coherence. Reverted for good.
//  R8 (KCHUNK=256, 1 block/CU = 1 wave/SIMD): 73.2us REGRESSION — TLP matters
//    more than partial bytes; 4 waves/CU can't hide the unroll-body bubble.
//  R9: KCHUNK=128 (NKC=64, same 16.8MB partials as R5) but CPT=2 ->
//      grid (16,64) = 1024 blocks = 4/CU = 16 waves/CU (2x R5's TLP),
//      unroll 16 (same 8KB/wave in flight).

constexpr int N_PREV = 8192;
constexpr int N_HID  = 8192;
constexpr int BATCH  = 8;
constexpr int TPB    = 256;
constexpr int CPT    = 2;                      // cols per thread (float2)
constexpr int COLS_PER_BLOCK = TPB * CPT;      // 512
constexpr int KCHUNK = 128;
constexpr int NKC    = N_PREV / KCHUNK;        // 64 k-chunks
constexpr int OUT_ELEMS = BATCH * N_HID;       // 65536

#define FMA2(A, S) A.x += (S) * w.x; A.y += (S) * w.y;

template <bool USE_ATOMIC>
__global__ __launch_bounds__(TPB) void snn_stage1(
    const float* __restrict__ spikes,
    const float* __restrict__ W,
    float* __restrict__ dst) {        // partial buffer, or out if USE_ATOMIC
  __shared__ float s_sp[KCHUNK][BATCH];        // k-major spikes chunk (4KB)

  const int cb  = blockIdx.x;
  const int p   = blockIdx.y;                  // k-chunk index
  const int k0  = p * KCHUNK;
  const int col = cb * COLS_PER_BLOCK + threadIdx.x * CPT;

  // Stage spikes chunk transposed; thread t writes float #t -> conflict-free.
  for (int t = threadIdx.x; t < KCHUNK * BATCH; t += TPB) {
    const int k = t >> 3, b = t & 7;
    s_sp[k][b] = spikes[b * N_PREV + k0 + k];
  }
  __syncthreads();

  // Named accumulators: guaranteed VGPRs (no private arrays anywhere).
  float2 a0 = {0,0}, a1 = {0,0}, a2 = {0,0}, a3 = {0,0};
  float2 a4 = {0,0}, a5 = {0,0}, a6 = {0,0}, a7 = {0,0};

  const float* wp = W + (size_t)k0 * N_HID + col;
  #pragma unroll 16
  for (int k = 0; k < KCHUNK; ++k) {
    const float2 w = *reinterpret_cast<const float2*>(wp);
    wp += N_HID;
    const float4 slo = *reinterpret_cast<const float4*>(&s_sp[k][0]); // b128 bcast
    const float4 shi = *reinterpret_cast<const float4*>(&s_sp[k][4]); // b128 bcast
    FMA2(a0, slo.x) FMA2(a1, slo.y) FMA2(a2, slo.z) FMA2(a3, slo.w)
    FMA2(a4, shi.x) FMA2(a5, shi.y) FMA2(a6, shi.z) FMA2(a7, shi.w)
  }

  if constexpr (USE_ATOMIC) {
    #define EMIT(b, A) { float* op = &dst[(b) * N_HID + col]; \
      atomicAdd(op+0, A.x); atomicAdd(op+1, A.y); }
    EMIT(0, a0) EMIT(1, a1) EMIT(2, a2) EMIT(3, a3)
    EMIT(4, a4) EMIT(5, a5) EMIT(6, a6) EMIT(7, a7)
    #undef EMIT
  } else {
    float* base = dst + (size_t)p * OUT_ELEMS + col;
    #define EMIT(b, A) *reinterpret_cast<float2*>(base + (b) * N_HID) = A;
    EMIT(0, a0) EMIT(1, a1) EMIT(2, a2) EMIT(3, a3)
    EMIT(4, a4) EMIT(5, a5) EMIT(6, a6) EMIT(7, a7)
    #undef EMIT
  }
}

// out[j4] = sum_p partial[p][j4]. One float4 per thread, 256 blocks x 64 thr.
constexpr int TPB2 = 64;

__global__ __launch_bounds__(TPB2) void snn_stage2(
    const float* __restrict__ partial, float* __restrict__ out) {
  const int j4 = blockIdx.x * TPB2 + threadIdx.x;    // 0..16383
  const float4* p4 = reinterpret_cast<const float4*>(partial) + j4;
  float4 s = {0,0,0,0};
  #pragma unroll 8
  for (int p = 0; p < NKC; ++p) {
    const float4 v = p4[(size_t)p * (OUT_ELEMS / 4)];
    s.x += v.x; s.y += v.y; s.z += v.z; s.w += v.w;
  }
  reinterpret_cast<float4*>(out)[j4] = s;
}

extern "C" void kernel_launch(void* const* d_in, const int* in_sizes, int n_in,
                              void* d_out, int out_size, void* d_ws, size_t ws_size,
                              hipStream_t stream) {
  const float* spikes = (const float*)d_in[0];   // [8, 8192]
  const float* W      = (const float*)d_in[1];   // [8192, 8192]
  float* out          = (float*)d_out;           // [8, 8192]
  float* partial      = (float*)d_ws;

  const size_t need = (size_t)NKC * OUT_ELEMS * sizeof(float);  // 16.8 MB
  dim3 grid(N_HID / COLS_PER_BLOCK, NKC);        // (16, 64) = 1024 blocks
  dim3 block(TPB);

  if (ws_size >= need) {
    snn_stage1<false><<<grid, block, 0, stream>>>(spikes, W, partial);
    snn_stage2<<<dim3(OUT_ELEMS / 4 / TPB2), dim3(TPB2), 0, stream>>>(partial, out);
  } else {
    // Fallback: atomics into zeroed out (deterministic host-side branch).
    (void)hipMemsetAsync(out, 0, (size_t)out_size * sizeof(float), stream);
    snn_stage1<true><<<grid, block, 0, stream>>>(spikes, W, out);
  }
}

// Round 10
// 59.712 us; speedup vs baseline: 1.2255x; 1.0405x over previous
//
#include <hip/hip_runtime.h>

// out[b][j] = sum_i spikes[b][i] * W[i][j]
//   spikes [8,8192] f32, W [8192,8192] f32 row-major, out [8,8192] f32.
// History:
//  R1 (float2, scalar LDS, atomics): 86us.
//  R2/R3 (acc ARRAY -> scratch + 8.4M atomics): 202-206us.
//  R4 (named float4 accs + two-stage split-K): 58.5us. R5 (wide stage-2): 58.2.
//  R6/R7 (nontemporal partials): post-timing divergence — nt breaks
//    cross-kernel producer->consumer coherence. Reverted for good.
//  R8 (KCHUNK=256 -> 4 waves/CU @ 16B): 73.2us — TLP-starved.
//  R9 (KCHUNK=128, CPT=2 -> 16 waves/CU @ 8B): 62.1us — issue-width-starved.
//  R10: the untested corner: 16 waves/CU @ 16B. KCHUNK=64 (NKC=128), CPT=4,
//       grid (8,128)=1024 blocks = 4/CU. Costs +16.8MB partial round-trip;
//       tests whether 8 waves/CU was still latency-limited.
//       (R2/R3 had this geometry but were scratch-crippled.)

constexpr int N_PREV = 8192;
constexpr int N_HID  = 8192;
constexpr int BATCH  = 8;
constexpr int TPB    = 256;
constexpr int CPT    = 4;                      // cols per thread (float4)
constexpr int COLS_PER_BLOCK = TPB * CPT;      // 1024
constexpr int KCHUNK = 64;
constexpr int NKC    = N_PREV / KCHUNK;        // 128 k-chunks
constexpr int OUT_ELEMS = BATCH * N_HID;       // 65536

#define FMA4(A, S) \
  A.x += (S) * w.x; A.y += (S) * w.y; A.z += (S) * w.z; A.w += (S) * w.w;

template <bool USE_ATOMIC>
__global__ __launch_bounds__(TPB) void snn_stage1(
    const float* __restrict__ spikes,
    const float* __restrict__ W,
    float* __restrict__ dst) {        // partial buffer, or out if USE_ATOMIC
  __shared__ float s_sp[KCHUNK][BATCH];        // k-major spikes chunk (2KB)

  const int cb  = blockIdx.x;
  const int p   = blockIdx.y;                  // k-chunk index
  const int k0  = p * KCHUNK;
  const int col = cb * COLS_PER_BLOCK + threadIdx.x * CPT;

  // Stage spikes chunk transposed; thread t writes float #t -> conflict-free.
  for (int t = threadIdx.x; t < KCHUNK * BATCH; t += TPB) {
    const int k = t >> 3, b = t & 7;
    s_sp[k][b] = spikes[b * N_PREV + k0 + k];
  }
  __syncthreads();

  // Named accumulators: guaranteed VGPRs (no private arrays anywhere).
  float4 a0 = {0,0,0,0}, a1 = {0,0,0,0}, a2 = {0,0,0,0}, a3 = {0,0,0,0};
  float4 a4 = {0,0,0,0}, a5 = {0,0,0,0}, a6 = {0,0,0,0}, a7 = {0,0,0,0};

  const float* wp = W + (size_t)k0 * N_HID + col;
  #pragma unroll 8
  for (int k = 0; k < KCHUNK; ++k) {
    const float4 w = *reinterpret_cast<const float4*>(wp);
    wp += N_HID;
    const float4 slo = *reinterpret_cast<const float4*>(&s_sp[k][0]); // b128 bcast
    const float4 shi = *reinterpret_cast<const float4*>(&s_sp[k][4]); // b128 bcast
    FMA4(a0, slo.x) FMA4(a1, slo.y) FMA4(a2, slo.z) FMA4(a3, slo.w)
    FMA4(a4, shi.x) FMA4(a5, shi.y) FMA4(a6, shi.z) FMA4(a7, shi.w)
  }

  if constexpr (USE_ATOMIC) {
    #define EMIT(b, A) { float* op = &dst[(b) * N_HID + col]; \
      atomicAdd(op+0, A.x); atomicAdd(op+1, A.y);             \
      atomicAdd(op+2, A.z); atomicAdd(op+3, A.w); }
    EMIT(0, a0) EMIT(1, a1) EMIT(2, a2) EMIT(3, a3)
    EMIT(4, a4) EMIT(5, a5) EMIT(6, a6) EMIT(7, a7)
    #undef EMIT
  } else {
    float* base = dst + (size_t)p * OUT_ELEMS + col;
    #define EMIT(b, A) *reinterpret_cast<float4*>(base + (b) * N_HID) = A;
    EMIT(0, a0) EMIT(1, a1) EMIT(2, a2) EMIT(3, a3)
    EMIT(4, a4) EMIT(5, a5) EMIT(6, a6) EMIT(7, a7)
    #undef EMIT
  }
}

// out[j4] = sum_p partial[p][j4]. One float4 per thread, 256 blocks x 64 thr.
constexpr int TPB2 = 64;

__global__ __launch_bounds__(TPB2) void snn_stage2(
    const float* __restrict__ partial, float* __restrict__ out) {
  const int j4 = blockIdx.x * TPB2 + threadIdx.x;    // 0..16383
  const float4* p4 = reinterpret_cast<const float4*>(partial) + j4;
  float4 s = {0,0,0,0};
  #pragma unroll 8
  for (int p = 0; p < NKC; ++p) {
    const float4 v = p4[(size_t)p * (OUT_ELEMS / 4)];
    s.x += v.x; s.y += v.y; s.z += v.z; s.w += v.w;
  }
  reinterpret_cast<float4*>(out)[j4] = s;
}

extern "C" void kernel_launch(void* const* d_in, const int* in_sizes, int n_in,
                              void* d_out, int out_size, void* d_ws, size_t ws_size,
                              hipStream_t stream) {
  const float* spikes = (const float*)d_in[0];   // [8, 8192]
  const float* W      = (const float*)d_in[1];   // [8192, 8192]
  float* out          = (float*)d_out;           // [8, 8192]
  float* partial      = (float*)d_ws;

  const size_t need = (size_t)NKC * OUT_ELEMS * sizeof(float);  // 33.6 MB
  dim3 grid(N_HID / COLS_PER_BLOCK, NKC);        // (8, 128) = 1024 blocks
  dim3 block(TPB);

  if (ws_size >= need) {
    snn_stage1<false><<<grid, block, 0, stream>>>(spikes, W, partial);
    snn_stage2<<<dim3(OUT_ELEMS / 4 / TPB2), dim3(TPB2), 0, stream>>>(partial, out);
  } else {
    // Fallback: atomics into zeroed out (deterministic host-side branch).
    (void)hipMemsetAsync(out, 0, (size_t)out_size * sizeof(float), stream);
    snn_stage1<true><<<grid, block, 0, stream>>>(spikes, W, out);
  }
}

// Round 11
// 58.662 us; speedup vs baseline: 1.2474x; 1.0179x over previous
//
#include <hip/hip_runtime.h>

// out[b][j] = sum_i spikes[b][i] * W[i][j]
//   spikes [8,8192] f32, W [8192,8192] f32 row-major, out [8,8192] f32.
// History:
//  R1 86us | R2/R3 202-206 (acc array->scratch + atomics) | R4 58.5 | R5 58.2
//  R6/R7 nt partials -> post-timing divergence (cross-kernel coherence). Ban nt.
//  R8 (4 waves/CU @16B): 73.2 — TLP-starved.
//  R9 (16 waves/CU @8B): 62.1 — issue-width-starved.
//  R10 (16 waves/CU @16B, 33.6MB partials): 59.7 — best per-byte (5.6 TB/s),
//      traffic overhead ate it. Best geometry = 16 waves + float4.
//  R11: two-level split-K keeps 128 k-splits (16 waves/CU) but only 32 global
//      slabs: 4-way in-block wave-split reduced via LDS, one partial write.
//      Partial round trip 67MB -> 16.8MB; full-wave 1KB W segments.

constexpr int N_PREV = 8192;
constexpr int N_HID  = 8192;
constexpr int BATCH  = 8;
constexpr int TPB    = 256;                    // 4 waves
constexpr int COLS_PER_BLOCK = 256;            // 64 lanes * float4
constexpr int KSLAB  = 256;                    // k-rows per block
constexpr int NSLAB  = N_PREV / KSLAB;         // 32 global slabs
constexpr int KWAVE  = KSLAB / 4;              // 64 k-rows per wave
constexpr int OUT_ELEMS = BATCH * N_HID;       // 65536

#define FMA4(A, S) \
  A.x += (S) * wv.x; A.y += (S) * wv.y; A.z += (S) * wv.z; A.w += (S) * wv.w;

template <bool USE_ATOMIC>
__global__ __launch_bounds__(TPB, 4) void snn_stage1(
    const float* __restrict__ spikes,
    const float* __restrict__ W,
    float* __restrict__ dst) {        // partial buffer, or out if USE_ATOMIC
  // 32KB, dual-purpose: [0..2047] spikes chunk during K-loop, then
  // [4][8][256] per-wave partials for the in-block reduction (barriered).
  __shared__ float smem[4 * BATCH * COLS_PER_BLOCK];

  const int cb   = blockIdx.x;
  const int p    = blockIdx.y;                 // k-slab index
  const int col0 = cb * COLS_PER_BLOCK;
  const int w    = threadIdx.x >> 6;           // wave 0..3 (in-block k-split)
  const int lane = threadIdx.x & 63;
  const int k0   = p * KSLAB;

  // Stage spikes chunk k-major: smem[k*8+b], k in [0,256). Conflict-free.
  for (int t = threadIdx.x; t < KSLAB * BATCH; t += TPB) {
    const int k = t >> 3, b = t & 7;
    smem[k * 8 + b] = spikes[b * N_PREV + k0 + k];
  }
  __syncthreads();

  // Named accumulators only (R2/R3 lesson: arrays get demoted to scratch).
  float4 a0 = {0,0,0,0}, a1 = {0,0,0,0}, a2 = {0,0,0,0}, a3 = {0,0,0,0};
  float4 a4 = {0,0,0,0}, a5 = {0,0,0,0}, a6 = {0,0,0,0}, a7 = {0,0,0,0};

  // Wave w owns k in [k0 + w*64, +64); whole wave reads 1KB contiguous W rows.
  const float* wp = W + (size_t)(k0 + w * KWAVE) * N_HID + col0 + 4 * lane;
  #pragma unroll 8
  for (int k = 0; k < KWAVE; ++k) {
    const float4 wv = *reinterpret_cast<const float4*>(wp);
    wp += N_HID;
    const float4 slo =
        *reinterpret_cast<const float4*>(&smem[(w * KWAVE + k) * 8]);     // bcast
    const float4 shi =
        *reinterpret_cast<const float4*>(&smem[(w * KWAVE + k) * 8 + 4]); // bcast
    FMA4(a0, slo.x) FMA4(a1, slo.y) FMA4(a2, slo.z) FMA4(a3, slo.w)
    FMA4(a4, shi.x) FMA4(a5, shi.y) FMA4(a6, shi.z) FMA4(a7, shi.w)
  }

  __syncthreads();   // spikes region dead; reuse smem for reduction

  // Per-wave partials: smem as [w][b][256] floats.
  #define ST(b, A) \
    *reinterpret_cast<float4*>(&smem[(w * BATCH + (b)) * COLS_PER_BLOCK + 4 * lane]) = A;
  ST(0, a0) ST(1, a1) ST(2, a2) ST(3, a3)
  ST(4, a4) ST(5, a5) ST(6, a6) ST(7, a7)
  #undef ST
  __syncthreads();

  // Reduce 4 waves -> 512 float4 outputs; 2 per thread. Then emit.
  const float4* s4 = reinterpret_cast<const float4*>(smem);
  #pragma unroll
  for (int i = 0; i < 2; ++i) {
    const int o  = threadIdx.x + TPB * i;      // 0..511
    const int b  = o >> 6, c4 = o & 63;
    const float4 v0 = s4[o], v1 = s4[512 + o], v2 = s4[1024 + o], v3 = s4[1536 + o];
    float4 r;
    r.x = (v0.x + v1.x) + (v2.x + v3.x);
    r.y = (v0.y + v1.y) + (v2.y + v3.y);
    r.z = (v0.z + v1.z) + (v2.z + v3.z);
    r.w = (v0.w + v1.w) + (v2.w + v3.w);
    if constexpr (USE_ATOMIC) {
      float* op = &dst[b * N_HID + col0 + 4 * c4];
      atomicAdd(op + 0, r.x); atomicAdd(op + 1, r.y);
      atomicAdd(op + 2, r.z); atomicAdd(op + 3, r.w);
    } else {
      *reinterpret_cast<float4*>(
          &dst[(size_t)p * OUT_ELEMS + b * N_HID + col0 + 4 * c4]) = r;
    }
  }
}

// out[j4] = sum_p partial[p][j4]. One float4 per thread, 256 blocks x 64 thr.
constexpr int TPB2 = 64;

__global__ __launch_bounds__(TPB2) void snn_stage2(
    const float* __restrict__ partial, float* __restrict__ out) {
  const int j4 = blockIdx.x * TPB2 + threadIdx.x;    // 0..16383
  const float4* p4 = reinterpret_cast<const float4*>(partial) + j4;
  float4 s = {0,0,0,0};
  #pragma unroll 8
  for (int p = 0; p < NSLAB; ++p) {
    const float4 v = p4[(size_t)p * (OUT_ELEMS / 4)];
    s.x += v.x; s.y += v.y; s.z += v.z; s.w += v.w;
  }
  reinterpret_cast<float4*>(out)[j4] = s;
}

extern "C" void kernel_launch(void* const* d_in, const int* in_sizes, int n_in,
                              void* d_out, int out_size, void* d_ws, size_t ws_size,
                              hipStream_t stream) {
  const float* spikes = (const float*)d_in[0];   // [8, 8192]
  const float* W      = (const float*)d_in[1];   // [8192, 8192]
  float* out          = (float*)d_out;           // [8, 8192]
  float* partial      = (float*)d_ws;

  const size_t need = (size_t)NSLAB * OUT_ELEMS * sizeof(float);  // 8.4 MB
  dim3 grid(N_HID / COLS_PER_BLOCK, NSLAB);      // (32, 32) = 1024 blocks
  dim3 block(TPB);

  if (ws_size >= need) {
    snn_stage1<false><<<grid, block, 0, stream>>>(spikes, W, partial);
    snn_stage2<<<dim3(OUT_ELEMS / 4 / TPB2), dim3(TPB2), 0, stream>>>(partial, out);
  } else {
    // Fallback: atomics into zeroed out (deterministic host-side branch).
    (void)hipMemsetAsync(out, 0, (size_t)out_size * sizeof(float), stream);
    snn_stage1<true><<<grid, block, 0, stream>>>(spikes, W, out);
  }
}